// Round 2
// baseline (83.371 us; speedup 1.0000x reference)
//
#include <hip/hip_runtime.h>
#include <math.h>

// ---------------------------------------------------------------------------
// out[b] = <Z0> of: [CNOT(1,0)·CNOT(0,1)·(Rot_l0 ⊗ Rot_l1)]^3 applied to
//          (RX(x0)|0>) ⊗ (RX(x1)|0>).
// Collapsed analytically to a 3x3 bilinear form:
//   out = (1, cos x0, sin x0) · G · (1, cos x1, sin x1)^T
//
// R7: split build_G (1 wave, full VGPR budget) from the streaming pass.
//     Result: 86.7 -> 83.1 us only. Occupancy was NOT the binding constraint.
// R8 (this round): lane-CONTIGUOUS streaming. The old loop read 64 B/lane
//     (4x float4 at lane-stride 64B): every global_load_dwordx4 touched 64
//     cache lines (one 16B sector each) = 4x the TA/L1 request processing
//     per byte; stores (lane-stride 32B) split lines the same way. Now each
//     lane reads ONE float4 (16B, wave = 1KB contiguous) = 2 element-pairs,
//     4 grid-strided slots per thread for MLP, float2 contiguous stores.
// ---------------------------------------------------------------------------

struct c32 { float re, im; };
__device__ __forceinline__ c32 cmul(c32 a, c32 b) { return { a.re*b.re - a.im*b.im, a.re*b.im + a.im*b.re }; }
__device__ __forceinline__ c32 cconj(c32 a) { return { a.re, -a.im }; }

__device__ __forceinline__ void build_G(const float* __restrict__ w, float* __restrict__ Gs)
{
    c32 M[4][4];
    #pragma unroll
    for (int i = 0; i < 4; ++i)
        #pragma unroll
        for (int j = 0; j < 4; ++j)
            M[i][j] = { (i == j) ? 1.f : 0.f, 0.f };

    #pragma unroll
    for (int l = 0; l < 3; ++l) {
        c32 U[2][2][2]; // [wire][row][col]
        #pragma unroll
        for (int q = 0; q < 2; ++q) {
            float phi   = w[(l*2 + q)*3 + 0];
            float theta = w[(l*2 + q)*3 + 1];
            float omega = w[(l*2 + q)*3 + 2];
            float c = __cosf(theta * 0.5f);
            float s = __sinf(theta * 0.5f);
            float ap = -0.5f * (phi + omega);   // ep = exp(i*ap)
            float am =  0.5f * (phi - omega);   // em = exp(i*am)
            c32 ep = { __cosf(ap), __sinf(ap) };
            c32 em = { __cosf(am), __sinf(am) };
            U[q][0][0] = {  ep.re * c,  ep.im * c };
            U[q][0][1] = { -em.re * s, -em.im * s };
            U[q][1][0] = {  em.re * s, -em.im * s };  // conj(em)*s
            U[q][1][1] = {  ep.re * c, -ep.im * c };  // conj(ep)*c
        }
        // A = kron(U0, U1)
        c32 A[4][4];
        #pragma unroll
        for (int j = 0; j < 2; ++j)
            #pragma unroll
            for (int k = 0; k < 2; ++k)
                #pragma unroll
                for (int jp = 0; jp < 2; ++jp)
                    #pragma unroll
                    for (int kp = 0; kp < 2; ++kp)
                        A[2*j + k][2*jp + kp] = cmul(U[0][j][jp], U[1][k][kp]);
        // CNOT(0,1): swap rows 2,3.  CNOT(1,0): swap rows 1,3.
        #pragma unroll
        for (int col = 0; col < 4; ++col) { c32 t = A[2][col]; A[2][col] = A[3][col]; A[3][col] = t; }
        #pragma unroll
        for (int col = 0; col < 4; ++col) { c32 t = A[1][col]; A[1][col] = A[3][col]; A[3][col] = t; }
        // M = A * M
        c32 NM[4][4];
        #pragma unroll
        for (int i = 0; i < 4; ++i)
            #pragma unroll
            for (int j = 0; j < 4; ++j) {
                c32 acc = {0.f, 0.f};
                #pragma unroll
                for (int k = 0; k < 4; ++k) { c32 t = cmul(A[i][k], M[k][j]); acc.re += t.re; acc.im += t.im; }
                NM[i][j] = acc;
            }
        #pragma unroll
        for (int i = 0; i < 4; ++i)
            #pragma unroll
            for (int j = 0; j < 4; ++j) M[i][j] = NM[i][j];
    }

    // H = M^dag D M, D = diag(1,1,-1,-1)
    const float Dv[4] = {1.f, 1.f, -1.f, -1.f};
    c32 H[4][4];
    #pragma unroll
    for (int a = 0; a < 4; ++a)
        #pragma unroll
        for (int b = 0; b < 4; ++b) {
            c32 acc = {0.f, 0.f};
            #pragma unroll
            for (int c = 0; c < 4; ++c) {
                c32 t = cmul(cconj(M[c][a]), M[c][b]);
                acc.re += Dv[c] * t.re;
                acc.im += Dv[c] * t.im;
            }
            H[a][b] = acc;
        }

    // phi = (1, -i, -i, -1); K_ab = Re(conj(phi_a) * phi_b * H_ab)
    const c32 ph[4] = { {1.f,0.f}, {0.f,-1.f}, {0.f,-1.f}, {-1.f,0.f} };
    float K[16];
    #pragma unroll
    for (int a = 0; a < 4; ++a)
        #pragma unroll
        for (int b = 0; b < 4; ++b) {
            c32 f = cmul(cconj(ph[a]), ph[b]);
            K[a*4 + b] = f.re * H[a][b].re - f.im * H[a][b].im;
        }

    // Collapse r^T K r (r over half-angles) to 3x3 bilinear form over
    // basis (1, cos x, sin x):
    const float P[2][2][3] = { { {0.5f, 0.5f, 0.f}, {0.f, 0.f, 0.5f} },
                               { {0.f,  0.f, 0.5f}, {0.5f,-0.5f, 0.f} } };
    #pragma unroll
    for (int p = 0; p < 3; ++p)
        #pragma unroll
        for (int q = 0; q < 3; ++q) {
            float g = 0.f;
            #pragma unroll
            for (int i = 0; i < 2; ++i)
                #pragma unroll
                for (int k = 0; k < 2; ++k)
                    #pragma unroll
                    for (int j = 0; j < 2; ++j)
                        #pragma unroll
                        for (int l = 0; l < 2; ++l)
                            g += K[(2*i + j)*4 + (2*k + l)] * P[i][k][p] * P[j][l][q];
            Gs[p*3 + q] = g;
        }
}

// Kernel 1: one wave, full VGPR budget -> the ~130-float build stays in
// registers with zero spills. Writes the 9-float G to workspace.
__global__ __launch_bounds__(64, 1) void build_G_kernel(const float* __restrict__ w,
                                                        float* __restrict__ G)
{
    if (threadIdx.x == 0) build_G(w, G);
}

__device__ __forceinline__ float eval_pair(float x0, float x1,
                                           float G0, float G1, float G2,
                                           float G3, float G4, float G5,
                                           float G6, float G7, float G8)
{
    float C0 = __cosf(x0), S0 = __sinf(x0);
    float C1 = __cosf(x1), S1 = __sinf(x1);
    float t0 = G0 + G1*C1 + G2*S1;
    float t1 = G3 + G4*C1 + G5*S1;
    float t2 = G6 + G7*C1 + G8*S1;
    return t0 + C0*t1 + S0*t2;
}

// Kernel 2: lane-contiguous streaming. Each lane: one float4 (= 2 element
// pairs) per slot, 4 grid-strided slots (4 independent loads in flight).
// Wave read = contiguous 1KB; wave write = contiguous 512B.
__global__ __launch_bounds__(256, 4) void qmain(const float4* __restrict__ x4,
                                                const float* __restrict__ Gp,
                                                float2* __restrict__ out2,
                                                int nc2 /* = B/2 */, int B)
{
    // 9 uniform loads -> SGPRs; L2-resident, broadcast.
    const float G0 = Gp[0], G1 = Gp[1], G2 = Gp[2];
    const float G3 = Gp[3], G4 = Gp[4], G5 = Gp[5];
    const float G6 = Gp[6], G7 = Gp[7], G8 = Gp[8];

    const int S = (int)(gridDim.x * blockDim.x);      // slot stride (lane-contiguous)
    const long long big = 4LL * S;                     // outer grid-stride
    for (long long base = (long long)blockIdx.x * blockDim.x + threadIdx.x;
         base < nc2; base += big) {
        const long long i0 = base;
        const long long i1 = base + S;
        const long long i2 = base + 2LL*S;
        const long long i3 = base + 3LL*S;
        if (i3 < nc2) {
            // fast path: 4 unconditional independent coalesced loads
            float4 v0 = x4[i0], v1 = x4[i1], v2 = x4[i2], v3 = x4[i3];
            out2[i0] = make_float2(eval_pair(v0.x, v0.y, G0,G1,G2,G3,G4,G5,G6,G7,G8),
                                   eval_pair(v0.z, v0.w, G0,G1,G2,G3,G4,G5,G6,G7,G8));
            out2[i1] = make_float2(eval_pair(v1.x, v1.y, G0,G1,G2,G3,G4,G5,G6,G7,G8),
                                   eval_pair(v1.z, v1.w, G0,G1,G2,G3,G4,G5,G6,G7,G8));
            out2[i2] = make_float2(eval_pair(v2.x, v2.y, G0,G1,G2,G3,G4,G5,G6,G7,G8),
                                   eval_pair(v2.z, v2.w, G0,G1,G2,G3,G4,G5,G6,G7,G8));
            out2[i3] = make_float2(eval_pair(v3.x, v3.y, G0,G1,G2,G3,G4,G5,G6,G7,G8),
                                   eval_pair(v3.z, v3.w, G0,G1,G2,G3,G4,G5,G6,G7,G8));
        } else {
            #pragma unroll
            for (int k = 0; k < 4; ++k) {
                long long i = base + (long long)k * S;
                if (i < nc2) {
                    float4 v = x4[i];
                    out2[i] = make_float2(eval_pair(v.x, v.y, G0,G1,G2,G3,G4,G5,G6,G7,G8),
                                          eval_pair(v.z, v.w, G0,G1,G2,G3,G4,G5,G6,G7,G8));
                }
            }
        }
    }

    // tail for odd B (B=4M is even; kept for generality)
    if ((B & 1) && blockIdx.x == 0 && threadIdx.x == 0) {
        const float* x = (const float*)x4;
        float* out = (float*)out2;
        long long b = B - 1;
        out[b] = eval_pair(x[2*b], x[2*b+1], G0,G1,G2,G3,G4,G5,G6,G7,G8);
    }
}

extern "C" void kernel_launch(void* const* d_in, const int* in_sizes, int n_in,
                              void* d_out, int out_size, void* d_ws, size_t ws_size,
                              hipStream_t stream)
{
    const float* x = (const float*)d_in[0];      // [B, 2]
    const float* w = (const float*)d_in[1];      // [3, 2, 3]
    float* out = (float*)d_out;                  // [B]
    float* G   = (float*)d_ws;                   // 9 floats of workspace
    const int B = in_sizes[0] / 2;
    const int nc2 = B >> 1;                      // float4 chunks (2 elems each)

    // Stage 1: build the 3x3 bilinear form once (1 wave; no spills at full
    // VGPR budget). Stage 2 is ordered after it on the stream.
    build_G_kernel<<<1, 64, 0, stream>>>(w, G);

    // Stage 2: lane-contiguous streaming pass. 2048 blocks x 256 threads,
    // 4 slots/thread covers nc2=2M chunks.
    qmain<<<2048, 256, 0, stream>>>((const float4*)x, G, (float2*)out, nc2, B);
}

// Round 3
// 79.166 us; speedup vs baseline: 1.0531x; 1.0531x over previous
//
#include <hip/hip_runtime.h>
#include <math.h>

// ---------------------------------------------------------------------------
// out[b] = <Z0> of: [CNOT(1,0)·CNOT(0,1)·(Rot_l0 ⊗ Rot_l1)]^3 applied to
//          (RX(x0)|0>) ⊗ (RX(x1)|0>).
// Collapsed analytically to a 3x3 bilinear form:
//   out = (1, cos x0, sin x0) · G · (1, cos x1, sin x1)^T
//
// R7:  split build/stream kernels          -> 83.1 us (occupancy not binding)
// R8:  lane-contiguous float4 streaming    -> 83.4 us (access pattern not
//      binding either: iteration is dominated by the harness's 256 MiB
//      poison fill @6.2 TB/s (44 us, at HBM ceiling) + dispatch train).
// R9 (this round): RE-MERGE into one kernel to drop the extra graph-node
//      launch + build dispatch (~2-5 us owned overhead). The old fused form
//      needed (256,1) because the serial ~130-float build spilled at a
//      64-VGPR budget. New build is LANE-PARALLEL and register-lean:
//        stage 1: lanes 0-3 evolve one column of M each (factored
//                 (U0 (x) U1) apply + CNOT row swaps, ~40 floats live),
//                 columns -> LDS.
//        stage 2: lanes 0-15 compute K[a][b] -> LDS.
//        stage 3: lanes 0-8 compute G[p][q]  -> LDS.
//      Fits (256,4) with no spills; build wall cost <1 us, paid once per
//      block (1024 persistent blocks = exactly full residency).
// ---------------------------------------------------------------------------

struct c32 { float re, im; };
__device__ __forceinline__ c32 cmul(c32 a, c32 b) { return { a.re*b.re - a.im*b.im, a.re*b.im + a.im*b.re }; }
__device__ __forceinline__ c32 cadd(c32 a, c32 b) { return { a.re + b.re, a.im + b.im }; }

__device__ __forceinline__ float eval_pair(float x0, float x1,
                                           float G0, float G1, float G2,
                                           float G3, float G4, float G5,
                                           float G6, float G7, float G8)
{
    float C0 = __cosf(x0), S0 = __sinf(x0);
    float C1 = __cosf(x1), S1 = __sinf(x1);
    float t0 = G0 + G1*C1 + G2*S1;
    float t1 = G3 + G4*C1 + G5*S1;
    float t2 = G6 + G7*C1 + G8*S1;
    return t0 + C0*t1 + S0*t2;
}

__global__ __launch_bounds__(256, 4) void qfused2(const float4* __restrict__ x4,
                                                  const float* __restrict__ w,
                                                  float2* __restrict__ out2,
                                                  int nc2 /* = B/2 */, int B)
{
    __shared__ float Mc[4][8];   // column a of M: entry c at [a][2c]=re,[a][2c+1]=im
    __shared__ float Ks[16];     // K[a*4+b]
    __shared__ float Gs[9];      // final 3x3 bilinear form

    const int tid = threadIdx.x;

    // ---- stage 1: lanes 0-3 each evolve one column of M (lockstep) --------
    if (tid < 4) {
        const int a = tid;
        c32 col[4];
        #pragma unroll
        for (int c = 0; c < 4; ++c) col[c] = { (c == a) ? 1.f : 0.f, 0.f };

        #pragma unroll
        for (int l = 0; l < 3; ++l) {
            c32 U0[2][2], U1[2][2];
            #pragma unroll
            for (int q = 0; q < 2; ++q) {
                float phi   = w[(l*2 + q)*3 + 0];
                float theta = w[(l*2 + q)*3 + 1];
                float omega = w[(l*2 + q)*3 + 2];
                float ch = __cosf(theta * 0.5f);
                float sh = __sinf(theta * 0.5f);
                float ap = -0.5f * (phi + omega);   // ep = exp(i*ap)
                float am =  0.5f * (phi - omega);   // em = exp(i*am)
                c32 ep = { __cosf(ap), __sinf(ap) };
                c32 em = { __cosf(am), __sinf(am) };
                c32 u00 = {  ep.re * ch,  ep.im * ch };
                c32 u01 = { -em.re * sh, -em.im * sh };
                c32 u10 = {  em.re * sh, -em.im * sh };  // conj(em)*sh
                c32 u11 = {  ep.re * ch, -ep.im * ch };  // conj(ep)*ch
                if (q == 0) { U0[0][0]=u00; U0[0][1]=u01; U0[1][0]=u10; U0[1][1]=u11; }
                else        { U1[0][0]=u00; U1[0][1]=u01; U1[1][0]=u10; U1[1][1]=u11; }
            }
            // pre[2j+k] = sum_{jp,kp} U0[j][jp] U1[k][kp] col[2jp+kp]
            // factored: t[jp][k] = sum_kp U1[k][kp] col[2jp+kp]
            c32 t[2][2];
            #pragma unroll
            for (int jp = 0; jp < 2; ++jp)
                #pragma unroll
                for (int k = 0; k < 2; ++k)
                    t[jp][k] = cadd(cmul(U1[k][0], col[2*jp + 0]),
                                    cmul(U1[k][1], col[2*jp + 1]));
            c32 pre[4];
            #pragma unroll
            for (int j = 0; j < 2; ++j)
                #pragma unroll
                for (int k = 0; k < 2; ++k)
                    pre[2*j + k] = cadd(cmul(U0[j][0], t[0][k]),
                                        cmul(U0[j][1], t[1][k]));
            // CNOT(0,1): swap rows 2,3.  CNOT(1,0): swap rows 1,3.
            { c32 s = pre[2]; pre[2] = pre[3]; pre[3] = s; }
            { c32 s = pre[1]; pre[1] = pre[3]; pre[3] = s; }
            #pragma unroll
            for (int c = 0; c < 4; ++c) col[c] = pre[c];
        }
        #pragma unroll
        for (int c = 0; c < 4; ++c) { Mc[a][2*c] = col[c].re; Mc[a][2*c+1] = col[c].im; }
    }
    __syncthreads();

    // ---- stage 2: lanes 0-15 compute K[a][b] -------------------------------
    if (tid < 16) {
        const int a = tid >> 2, b = tid & 3;
        // H[a][b] = sum_c Dv[c] * conj(M[c][a]) * M[c][b],  Dv = (1,1,-1,-1)
        float Hre = 0.f, Him = 0.f;
        #pragma unroll
        for (int c = 0; c < 4; ++c) {
            float ar = Mc[a][2*c], ai = Mc[a][2*c+1];
            float br = Mc[b][2*c], bi = Mc[b][2*c+1];
            float re = ar*br + ai*bi;           // conj(Ma_c) * Mb_c
            float im = ar*bi - ai*br;
            float d = (c < 2) ? 1.f : -1.f;
            Hre += d * re;
            Him += d * im;
        }
        // phi = (1, -i, -i, -1); f = conj(ph[a]) * ph[b]
        float par = (a == 0) ? 1.f : ((a == 3) ? -1.f : 0.f);
        float pai = (a == 1 || a == 2) ? -1.f : 0.f;
        float pbr = (b == 0) ? 1.f : ((b == 3) ? -1.f : 0.f);
        float pbi = (b == 1 || b == 2) ? -1.f : 0.f;
        c32 f = cmul({par, -pai}, {pbr, pbi});
        Ks[tid] = f.re * Hre - f.im * Him;
    }
    __syncthreads();

    // ---- stage 3: lanes 0-8 compute G[p][q] --------------------------------
    if (tid < 9) {
        const int p = (tid >= 6) ? 2 : ((tid >= 3) ? 1 : 0);
        const int q = tid - 3*p;
        // P[i][k][p]: p=0 -> [[.5,0],[0,.5]]; p=1 -> [[.5,0],[0,-.5]]; p=2 -> [[0,.5],[.5,0]]
        float Pa[2][2], Pb[2][2];
        Pa[0][0] = (p == 2) ? 0.f : 0.5f;
        Pa[0][1] = (p == 2) ? 0.5f : 0.f;
        Pa[1][0] = Pa[0][1];
        Pa[1][1] = (p == 0) ? 0.5f : ((p == 1) ? -0.5f : 0.f);
        Pb[0][0] = (q == 2) ? 0.f : 0.5f;
        Pb[0][1] = (q == 2) ? 0.5f : 0.f;
        Pb[1][0] = Pb[0][1];
        Pb[1][1] = (q == 0) ? 0.5f : ((q == 1) ? -0.5f : 0.f);
        float g = 0.f;
        #pragma unroll
        for (int i = 0; i < 2; ++i)
            #pragma unroll
            for (int k = 0; k < 2; ++k)
                #pragma unroll
                for (int j = 0; j < 2; ++j)
                    #pragma unroll
                    for (int l = 0; l < 2; ++l)
                        g += Ks[(2*i + j)*4 + (2*k + l)] * Pa[i][k] * Pb[j][l];
        Gs[tid] = g;
    }
    __syncthreads();

    // ---- streaming (identical math to R8's verified qmain) -----------------
    const float G0 = Gs[0], G1 = Gs[1], G2 = Gs[2];
    const float G3 = Gs[3], G4 = Gs[4], G5 = Gs[5];
    const float G6 = Gs[6], G7 = Gs[7], G8 = Gs[8];

    const int S = (int)(gridDim.x * blockDim.x);      // slot stride (lane-contiguous)
    const long long big = 4LL * S;                     // outer grid-stride
    for (long long base = (long long)blockIdx.x * blockDim.x + threadIdx.x;
         base < nc2; base += big) {
        const long long i0 = base;
        const long long i1 = base + S;
        const long long i2 = base + 2LL*S;
        const long long i3 = base + 3LL*S;
        if (i3 < nc2) {
            float4 v0 = x4[i0], v1 = x4[i1], v2 = x4[i2], v3 = x4[i3];
            out2[i0] = make_float2(eval_pair(v0.x, v0.y, G0,G1,G2,G3,G4,G5,G6,G7,G8),
                                   eval_pair(v0.z, v0.w, G0,G1,G2,G3,G4,G5,G6,G7,G8));
            out2[i1] = make_float2(eval_pair(v1.x, v1.y, G0,G1,G2,G3,G4,G5,G6,G7,G8),
                                   eval_pair(v1.z, v1.w, G0,G1,G2,G3,G4,G5,G6,G7,G8));
            out2[i2] = make_float2(eval_pair(v2.x, v2.y, G0,G1,G2,G3,G4,G5,G6,G7,G8),
                                   eval_pair(v2.z, v2.w, G0,G1,G2,G3,G4,G5,G6,G7,G8));
            out2[i3] = make_float2(eval_pair(v3.x, v3.y, G0,G1,G2,G3,G4,G5,G6,G7,G8),
                                   eval_pair(v3.z, v3.w, G0,G1,G2,G3,G4,G5,G6,G7,G8));
        } else {
            #pragma unroll
            for (int k = 0; k < 4; ++k) {
                long long i = base + (long long)k * S;
                if (i < nc2) {
                    float4 v = x4[i];
                    out2[i] = make_float2(eval_pair(v.x, v.y, G0,G1,G2,G3,G4,G5,G6,G7,G8),
                                          eval_pair(v.z, v.w, G0,G1,G2,G3,G4,G5,G6,G7,G8));
                }
            }
        }
    }

    // tail for odd B (B=4M is even; kept for generality)
    if ((B & 1) && blockIdx.x == 0 && threadIdx.x == 0) {
        const float* x = (const float*)x4;
        float* out = (float*)out2;
        long long b = B - 1;
        out[b] = eval_pair(x[2*b], x[2*b+1], G0,G1,G2,G3,G4,G5,G6,G7,G8);
    }
}

extern "C" void kernel_launch(void* const* d_in, const int* in_sizes, int n_in,
                              void* d_out, int out_size, void* d_ws, size_t ws_size,
                              hipStream_t stream)
{
    const float* x = (const float*)d_in[0];      // [B, 2]
    const float* w = (const float*)d_in[1];      // [3, 2, 3]
    float* out = (float*)d_out;                  // [B]
    const int B = in_sizes[0] / 2;
    const int nc2 = B >> 1;                      // float4 chunks (2 elems each)

    // Single fused dispatch: 1024 blocks x 256 threads = exactly full
    // residency at (256,4); every block builds G once (lane-parallel, <1 us)
    // then grid-strides the streaming pass (8 float4 slots/thread at B=4M).
    qfused2<<<1024, 256, 0, stream>>>((const float4*)x, w, (float2*)out, nc2, B);
}